// Round 8
// baseline (67.880 us; speedup 1.0000x reference)
//
#include <hip/hip_runtime.h>
#include <hip/hip_bf16.h>

// LiquidS4: y = (scan(a, u@B.T)) @ C.T + D*u
// u (4,4096,1024) f32; Lambda (64); log_dt (1); B (64,1024); C (1024,64); D (1024)
// 3-kernel pipeline: bu_scan (GEMM + 4-wave chunk scan) -> carry_scan(+dec) -> y_gemm.

constexpr int BATCH  = 4;
constexpr int L      = 4096;
constexpr int DM     = 1024;
constexpr int N      = 64;
constexpr int ROWS   = BATCH * L;    // 16384
constexpr int CHUNK  = 64;           // one chunk per bu_scan block
constexpr int NCHUNK = L / CHUNK;    // 64

typedef __attribute__((ext_vector_type(8))) short     bf16x8;
typedef __attribute__((ext_vector_type(4))) float     f32x4;

__device__ __forceinline__ unsigned int pk2(float x, float y) {
  __hip_bfloat162 h = __float22bfloat162_rn(make_float2(x, y));   // v_cvt_pk_bf16_f32
  return *reinterpret_cast<unsigned int*>(&h);
}

// ---------------- Kernel 1: Bu = u @ B.T (bf16 MFMA) + 4-wave chunk scan ------
// Block = 64 rows = one scan chunk. 2-deep register prefetch; Bu stays in LDS.
__global__ __launch_bounds__(256) void bu_scan(const float* __restrict__ u,
                                               const float* __restrict__ Bm,
                                               const float* __restrict__ Lambda,
                                               const float* __restrict__ log_dt,
                                               unsigned short* __restrict__ xsb,
                                               float* __restrict__ F) {
  __shared__ __align__(16) char smem[36864];
  typedef unsigned short HalfT[64][72];
  HalfT* As = reinterpret_cast<HalfT*>(smem);               // [2][64][72] = 18432 B
  HalfT* Bs = reinterpret_cast<HalfT*>(smem + 18432);       // [2][64][72] = 18432 B
  float (*T)[68] = reinterpret_cast<float (*)[68]>(smem);   // 17408 B (unions As)
  float* W = reinterpret_cast<float*>(smem + 17408);        // 1024 B  (unions As)

  const int tid  = threadIdx.x;
  const int lane = tid & 63;
  const int wv   = tid >> 6;           // wave 0..3
  const int l15  = lane & 15;
  const int g    = lane >> 4;
  const int row0 = blockIdx.x * 64;

  const int sr = tid >> 4;             // staging row 0..15 (+i*16)
  const int sq = tid & 15;             // staging k-quad

  f32x4 acc[4] = {};
  float4 pa[2][4], pb[2][4];

  constexpr int NCH = DM / 64;         // 16 K-chunks
  // prologue: chunks 0,1 -> reg sets 0,1 (2-deep)
  #pragma unroll
  for (int s = 0; s < 2; ++s) {
    const int kb = s * 64;
    #pragma unroll
    for (int i = 0; i < 4; ++i) {
      const int r = sr + i * 16;
      pa[s][i] = *reinterpret_cast<const float4*>(&u[(long)(row0 + r) * DM + kb + sq * 4]);
      pb[s][i] = *reinterpret_cast<const float4*>(&Bm[(long)r * DM + kb + sq * 4]);
    }
  }

  for (int c = 0; c < NCH; ++c) {
    const int s = c & 1;
    if (c) __syncthreads();
    #pragma unroll
    for (int i = 0; i < 4; ++i) {
      const int r = sr + i * 16;
      uint2 ha = {pk2(pa[s][i].x, pa[s][i].y), pk2(pa[s][i].z, pa[s][i].w)};
      uint2 hb = {pk2(pb[s][i].x, pb[s][i].y), pk2(pb[s][i].z, pb[s][i].w)};
      *reinterpret_cast<uint2*>(&As[s][r][sq * 4]) = ha;
      *reinterpret_cast<uint2*>(&Bs[s][r][sq * 4]) = hb;
    }
    __syncthreads();
    if (c + 2 < NCH) {                 // refill the set just consumed (2 chunks ahead)
      const int kb = (c + 2) * 64;
      #pragma unroll
      for (int i = 0; i < 4; ++i) {
        const int r = sr + i * 16;
        pa[s][i] = *reinterpret_cast<const float4*>(&u[(long)(row0 + r) * DM + kb + sq * 4]);
        pb[s][i] = *reinterpret_cast<const float4*>(&Bm[(long)r * DM + kb + sq * 4]);
      }
    }
    #pragma unroll
    for (int ks = 0; ks < 2; ++ks) {
      const bf16x8 af = *reinterpret_cast<const bf16x8*>(
          &As[s][wv * 16 + l15][ks * 32 + g * 8]);
      #pragma unroll
      for (int t = 0; t < 4; ++t) {
        const bf16x8 bfr = *reinterpret_cast<const bf16x8*>(
            &Bs[s][t * 16 + l15][ks * 32 + g * 8]);
        acc[t] = __builtin_amdgcn_mfma_f32_16x16x32_bf16(af, bfr, acc[t], 0, 0, 0);
      }
    }
  }

  // Bu tile -> LDS transpose (col n = t*16+l15, row = wv*16+g*4+r)
  __syncthreads();
  #pragma unroll
  for (int t = 0; t < 4; ++t)
    #pragma unroll
    for (int r = 0; r < 4; ++r)
      T[wv * 16 + g * 4 + r][t * 16 + l15] = acc[t][r];
  __syncthreads();

  // ---- 4-wave parallel scan: wave w owns timesteps w*16..w*16+15, lane = n ---
  const float dtv = __expf(log_dt[0]);
  const float wn  = -dtv * __expf(Lambda[lane]);
  const float a   = __expf(wn);
  const float a16 = __expf(wn * 16.0f);

  float p[16];
  {
    float x = 0.0f;
    #pragma unroll
    for (int j = 0; j < 16; ++j) { x = fmaf(a, x, T[wv * 16 + j][lane]); p[j] = x; }
    W[wv * 64 + lane] = x;             // wave-local final
  }
  __syncthreads();
  float P = 0.0f;                      // prefix entering this wave's 16 steps
  #pragma unroll
  for (int w2 = 0; w2 < 3; ++w2)
    if (w2 < wv) P = fmaf(a16, P, W[w2 * 64 + lane]);
  __syncthreads();                     // W consumed before T overwrite (same union? W!=T rows ok; keep for safety)
  float cfac = P;
  #pragma unroll
  for (int j = 0; j < 16; ++j) { cfac *= a; T[wv * 16 + j][lane] = p[j] + cfac; }
  if (wv == 3) F[blockIdx.x * N + lane] = p[15] + cfac;   // chunk final
  __syncthreads();

  // coalesced bf16 stores of the scanned tile: 64 rows x 64 n
  #pragma unroll
  for (int i = 0; i < 4; ++i) {
    const int idx = tid + i * 256;
    const int r = idx >> 4, q = idx & 15;
    const float4 v = *reinterpret_cast<const float4*>(&T[r][q * 4]);
    uint2 o = {pk2(v.x, v.y), pk2(v.z, v.w)};
    *reinterpret_cast<uint2*>(&xsb[(long)(row0 + r) * N + q * 4]) = o;
  }
}

// ---------------- Kernel 2: carry over chunk finals + dec table ---------------
__global__ __launch_bounds__(256) void carry_scan(const float* __restrict__ F,
                                                  const float* __restrict__ Lambda,
                                                  const float* __restrict__ log_dt,
                                                  float* __restrict__ carry,
                                                  float* __restrict__ dec) {
  const int t = threadIdx.x;
  const int b = t >> 6;
  const int n = t & 63;
  const float dt = __expf(log_dt[0]);
  const float w  = -dt * __expf(Lambda[n]);
  const float aS = __expf(w * (float)CHUNK);

  // dec[t][n] = a^(t+1), t = 0..63 (thread-group b covers 16 timesteps)
  #pragma unroll
  for (int i = 0; i < 16; ++i) {
    const int tt = b * 16 + i;
    dec[tt * N + n] = __expf(w * (float)(tt + 1));
  }

  float f[NCHUNK];
  #pragma unroll
  for (int c = 0; c < NCHUNK; ++c) f[c] = F[(b * NCHUNK + c) * N + n];

  float P = 0.0f;
  #pragma unroll
  for (int c = 0; c < NCHUNK; ++c) {
    carry[(b * NCHUNK + c) * N + n] = P;
    P = fmaf(aS, P, f[c]);
  }
}

// ---------------- Kernel 3: y = (xs + dec*carry) @ C.T (+D*u if D!=0) ---------
// Tile 64 rows x 128 d; bf16 MFMA; LDS-transpose epilogue -> float4 stores.
__global__ __launch_bounds__(256) void y_gemm(const unsigned short* __restrict__ xsb,
                                              const float* __restrict__ carry,
                                              const float* __restrict__ dec,
                                              const float* __restrict__ Cm,
                                              const float* __restrict__ Dv,
                                              const float* __restrict__ u,
                                              float* __restrict__ y) {
  __shared__ __align__(16) char smem[33792];
  unsigned short (*Xs)[72] = reinterpret_cast<unsigned short (*)[72]>(smem);         // 9216 B
  unsigned short (*Cs)[72] = reinterpret_cast<unsigned short (*)[72]>(smem + 9216);  // 18432 B
  float (*T)[132] = reinterpret_cast<float (*)[132]>(smem);                          // 33792 B union
  __shared__ float ciS[64], Dsh[128];

  const int tid  = threadIdx.x;
  const int lane = tid & 63;
  const int wv   = tid >> 6;
  const int l15  = lane & 15;
  const int g    = lane >> 4;
  const int row0 = (blockIdx.x & 255) * 64;
  const int d0   = (blockIdx.x >> 8) * 128;

  if (tid < 64)  ciS[tid] = carry[row0 + tid];   // (row0/64)*64 + n == row0 + n
  if (tid < 128) Dsh[tid] = Dv[d0 + tid];
  __syncthreads();

  // stage Xs with carry fixup: 512 ushort8 groups (2 per thread)
  #pragma unroll
  for (int i = 0; i < 2; ++i) {
    const int idx = tid + i * 256;
    const int r = idx >> 3, q = idx & 7;       // r 0..63, q = n-octet
    const uint4 xv = *reinterpret_cast<const uint4*>(&xsb[(long)(row0 + r) * N + q * 8]);
    const float4 dv0 = *reinterpret_cast<const float4*>(&dec[r * N + q * 8]);
    const float4 dv1 = *reinterpret_cast<const float4*>(&dec[r * N + q * 8 + 4]);
    float f[8];
    #pragma unroll
    for (int j = 0; j < 4; ++j) {
      const unsigned int wbits = (&xv.x)[j];
      f[2 * j]     = __uint_as_float(wbits << 16);
      f[2 * j + 1] = __uint_as_float(wbits & 0xFFFF0000u);
    }
    f[0] = fmaf(dv0.x, ciS[q * 8 + 0], f[0]);
    f[1] = fmaf(dv0.y, ciS[q * 8 + 1], f[1]);
    f[2] = fmaf(dv0.z, ciS[q * 8 + 2], f[2]);
    f[3] = fmaf(dv0.w, ciS[q * 8 + 3], f[3]);
    f[4] = fmaf(dv1.x, ciS[q * 8 + 4], f[4]);
    f[5] = fmaf(dv1.y, ciS[q * 8 + 5], f[5]);
    f[6] = fmaf(dv1.z, ciS[q * 8 + 6], f[6]);
    f[7] = fmaf(dv1.w, ciS[q * 8 + 7], f[7]);
    uint4 o = {pk2(f[0], f[1]), pk2(f[2], f[3]), pk2(f[4], f[5]), pk2(f[6], f[7])};
    *reinterpret_cast<uint4*>(&Xs[r][q * 8]) = o;
  }
  // stage Cs from f32 (L2-hot): 128 d x 64 n, 8 float4/thread
  #pragma unroll
  for (int i = 0; i < 8; ++i) {
    const int idx = tid + i * 256;
    const int r = idx >> 4, q = idx & 15;
    const float4 v = *reinterpret_cast<const float4*>(&Cm[(long)(d0 + r) * N + q * 4]);
    uint2 o = {pk2(v.x, v.y), pk2(v.z, v.w)};
    *reinterpret_cast<uint2*>(&Cs[r][q * 4]) = o;
  }
  __syncthreads();

  bf16x8 af[2];
  #pragma unroll
  for (int ks = 0; ks < 2; ++ks)
    af[ks] = *reinterpret_cast<const bf16x8*>(&Xs[wv * 16 + l15][ks * 32 + g * 8]);

  f32x4 acc[8] = {};
  #pragma unroll
  for (int t = 0; t < 8; ++t) {
    #pragma unroll
    for (int ks = 0; ks < 2; ++ks) {
      const bf16x8 bfr = *reinterpret_cast<const bf16x8*>(
          &Cs[t * 16 + l15][ks * 32 + g * 8]);
      acc[t] = __builtin_amdgcn_mfma_f32_16x16x32_bf16(af[ks], bfr, acc[t], 0, 0, 0);
    }
  }

  // transpose via LDS -> coalesced float4 stores
  __syncthreads();
  #pragma unroll
  for (int t = 0; t < 8; ++t)
    #pragma unroll
    for (int r = 0; r < 4; ++r)
      T[wv * 16 + g * 4 + r][t * 16 + l15] = acc[t][r];
  __syncthreads();

  #pragma unroll
  for (int i = 0; i < 8; ++i) {
    const int id = tid + i * 256;
    const int r = id >> 5;
    const int q = id & 31;
    float4 v = *reinterpret_cast<const float4*>(&T[r][q * 4]);
    const float4 dd = *reinterpret_cast<const float4*>(&Dsh[q * 4]);
    if (dd.x != 0.0f || dd.y != 0.0f || dd.z != 0.0f || dd.w != 0.0f) {
      const float4 uu = *reinterpret_cast<const float4*>(
          &u[(long)(row0 + r) * DM + d0 + q * 4]);
      v.x = fmaf(dd.x, uu.x, v.x);
      v.y = fmaf(dd.y, uu.y, v.y);
      v.z = fmaf(dd.z, uu.z, v.z);
      v.w = fmaf(dd.w, uu.w, v.w);
    }
    *reinterpret_cast<float4*>(&y[(long)(row0 + r) * DM + d0 + q * 4]) = v;
  }
}

extern "C" void kernel_launch(void* const* d_in, const int* in_sizes, int n_in,
                              void* d_out, int out_size, void* d_ws, size_t ws_size,
                              hipStream_t stream) {
  const float* u      = (const float*)d_in[0];
  const float* Lambda = (const float*)d_in[1];
  const float* log_dt = (const float*)d_in[2];
  const float* Bm     = (const float*)d_in[3];
  const float* Cm     = (const float*)d_in[4];
  const float* Dv     = (const float*)d_in[5];
  float* y = (float*)d_out;

  const size_t planeB = (size_t)ROWS * N;              // 1M elems
  unsigned short* xsb = (unsigned short*)d_ws;         // 2 MB bf16
  float* F     = (float*)(xsb + planeB);               // 64 KB
  float* carry = F + (size_t)BATCH * NCHUNK * N;       // 64 KB
  float* dec   = carry + (size_t)BATCH * NCHUNK * N;   // 16 KB

  bu_scan<<<ROWS / 64, 256, 0, stream>>>(u, Bm, Lambda, log_dt, xsb, F);
  carry_scan<<<1, 256, 0, stream>>>(F, Lambda, log_dt, carry, dec);
  y_gemm<<<(ROWS / 64) * (DM / 128), 256, 0, stream>>>(xsb, carry, dec, Cm, Dv, u, y);
}

// Round 9
// 36.072 us; speedup vs baseline: 1.8818x; 1.8818x over previous
//
#include <hip/hip_runtime.h>
#include <hip/hip_bf16.h>

// LiquidS4: y = (scan(a, u@B.T)) @ C.T + D*u
// u (4,4096,1024) f32; Lambda (64); log_dt (1); B (64,1024); C (1024,64); D (1024)
// 3-kernel pipeline: bu_scan (GEMM + 4-wave chunk scan) -> carry_scan(+dec) -> y_gemm.
// R9: K-loop fully unrolled so the 2-deep prefetch sets index with compile-time
// constants (rule #20 fix — R8's runtime [c&1] sent pa/pb to scratch: 90 MB spill).

constexpr int BATCH  = 4;
constexpr int L      = 4096;
constexpr int DM     = 1024;
constexpr int N      = 64;
constexpr int ROWS   = BATCH * L;    // 16384
constexpr int CHUNK  = 64;           // one chunk per bu_scan block
constexpr int NCHUNK = L / CHUNK;    // 64

typedef __attribute__((ext_vector_type(8))) short     bf16x8;
typedef __attribute__((ext_vector_type(4))) float     f32x4;

__device__ __forceinline__ unsigned int pk2(float x, float y) {
  __hip_bfloat162 h = __float22bfloat162_rn(make_float2(x, y));   // v_cvt_pk_bf16_f32
  return *reinterpret_cast<unsigned int*>(&h);
}

// ---------------- Kernel 1: Bu = u @ B.T (bf16 MFMA) + 4-wave chunk scan ------
__global__ __launch_bounds__(256) void bu_scan(const float* __restrict__ u,
                                               const float* __restrict__ Bm,
                                               const float* __restrict__ Lambda,
                                               const float* __restrict__ log_dt,
                                               unsigned short* __restrict__ xsb,
                                               float* __restrict__ F) {
  __shared__ __align__(16) char smem[36864];
  typedef unsigned short HalfT[64][72];
  HalfT* As = reinterpret_cast<HalfT*>(smem);               // [2][64][72] = 18432 B
  HalfT* Bs = reinterpret_cast<HalfT*>(smem + 18432);       // [2][64][72] = 18432 B
  float (*T)[68] = reinterpret_cast<float (*)[68]>(smem);   // 17408 B (unions As)
  float* W = reinterpret_cast<float*>(smem + 17408);        // 1024 B  (unions As tail)

  const int tid  = threadIdx.x;
  const int lane = tid & 63;
  const int wv   = tid >> 6;           // wave 0..3
  const int l15  = lane & 15;
  const int g    = lane >> 4;
  const int row0 = blockIdx.x * 64;

  const int sr = tid >> 4;             // staging row 0..15 (+i*16)
  const int sq = tid & 15;             // staging k-quad

  f32x4 acc[4] = {};
  float4 pa[2][4], pb[2][4];

  constexpr int NCH = DM / 64;         // 16 K-chunks
  // prologue: chunks 0,1 -> reg sets 0,1 (2-deep)
  #pragma unroll
  for (int s = 0; s < 2; ++s) {
    const int kb = s * 64;
    #pragma unroll
    for (int i = 0; i < 4; ++i) {
      const int r = sr + i * 16;
      pa[s][i] = *reinterpret_cast<const float4*>(&u[(long)(row0 + r) * DM + kb + sq * 4]);
      pb[s][i] = *reinterpret_cast<const float4*>(&Bm[(long)r * DM + kb + sq * 4]);
    }
  }

  #pragma unroll                       // FULL unroll: s/buf become compile-time
  for (int c = 0; c < NCH; ++c) {
    const int s = c & 1;
    if (c) __syncthreads();
    #pragma unroll
    for (int i = 0; i < 4; ++i) {
      const int r = sr + i * 16;
      uint2 ha = {pk2(pa[s][i].x, pa[s][i].y), pk2(pa[s][i].z, pa[s][i].w)};
      uint2 hb = {pk2(pb[s][i].x, pb[s][i].y), pk2(pb[s][i].z, pb[s][i].w)};
      *reinterpret_cast<uint2*>(&As[s][r][sq * 4]) = ha;
      *reinterpret_cast<uint2*>(&Bs[s][r][sq * 4]) = hb;
    }
    __syncthreads();
    if (c + 2 < NCH) {                 // refill the set just consumed (2 ahead)
      const int kb = (c + 2) * 64;
      #pragma unroll
      for (int i = 0; i < 4; ++i) {
        const int r = sr + i * 16;
        pa[s][i] = *reinterpret_cast<const float4*>(&u[(long)(row0 + r) * DM + kb + sq * 4]);
        pb[s][i] = *reinterpret_cast<const float4*>(&Bm[(long)r * DM + kb + sq * 4]);
      }
    }
    #pragma unroll
    for (int ks = 0; ks < 2; ++ks) {
      const bf16x8 af = *reinterpret_cast<const bf16x8*>(
          &As[s][wv * 16 + l15][ks * 32 + g * 8]);
      #pragma unroll
      for (int t = 0; t < 4; ++t) {
        const bf16x8 bfr = *reinterpret_cast<const bf16x8*>(
            &Bs[s][t * 16 + l15][ks * 32 + g * 8]);
        acc[t] = __builtin_amdgcn_mfma_f32_16x16x32_bf16(af, bfr, acc[t], 0, 0, 0);
      }
    }
  }

  // Bu tile -> LDS transpose (col n = t*16+l15, row = wv*16+g*4+r)
  __syncthreads();
  #pragma unroll
  for (int t = 0; t < 4; ++t)
    #pragma unroll
    for (int r = 0; r < 4; ++r)
      T[wv * 16 + g * 4 + r][t * 16 + l15] = acc[t][r];
  __syncthreads();

  // ---- 4-wave parallel scan: wave w owns timesteps w*16..w*16+15, lane = n ---
  const float dtv = __expf(log_dt[0]);
  const float wn  = -dtv * __expf(Lambda[lane]);
  const float a   = __expf(wn);
  const float a16 = __expf(wn * 16.0f);

  float p[16];
  {
    float x = 0.0f;
    #pragma unroll
    for (int j = 0; j < 16; ++j) { x = fmaf(a, x, T[wv * 16 + j][lane]); p[j] = x; }
    W[wv * 64 + lane] = x;             // wave-local final
  }
  __syncthreads();
  float P = 0.0f;                      // prefix entering this wave's 16 steps
  #pragma unroll
  for (int w2 = 0; w2 < 3; ++w2)
    if (w2 < wv) P = fmaf(a16, P, W[w2 * 64 + lane]);
  __syncthreads();
  float cfac = P;
  #pragma unroll
  for (int j = 0; j < 16; ++j) { cfac *= a; T[wv * 16 + j][lane] = p[j] + cfac; }
  if (wv == 3) F[blockIdx.x * N + lane] = p[15] + cfac;   // chunk final
  __syncthreads();

  // coalesced bf16 stores of the scanned tile: 64 rows x 64 n
  #pragma unroll
  for (int i = 0; i < 4; ++i) {
    const int idx = tid + i * 256;
    const int r = idx >> 4, q = idx & 15;
    const float4 v = *reinterpret_cast<const float4*>(&T[r][q * 4]);
    uint2 o = {pk2(v.x, v.y), pk2(v.z, v.w)};
    *reinterpret_cast<uint2*>(&xsb[(long)(row0 + r) * N + q * 4]) = o;
  }
}

// ---------------- Kernel 2: carry over chunk finals + dec table ---------------
__global__ __launch_bounds__(256) void carry_scan(const float* __restrict__ F,
                                                  const float* __restrict__ Lambda,
                                                  const float* __restrict__ log_dt,
                                                  float* __restrict__ carry,
                                                  float* __restrict__ dec) {
  const int t = threadIdx.x;
  const int b = t >> 6;
  const int n = t & 63;
  const float dt = __expf(log_dt[0]);
  const float w  = -dt * __expf(Lambda[n]);
  const float aS = __expf(w * (float)CHUNK);

  #pragma unroll
  for (int i = 0; i < 16; ++i) {
    const int tt = b * 16 + i;
    dec[tt * N + n] = __expf(w * (float)(tt + 1));
  }

  float f[NCHUNK];
  #pragma unroll
  for (int c = 0; c < NCHUNK; ++c) f[c] = F[(b * NCHUNK + c) * N + n];

  float P = 0.0f;
  #pragma unroll
  for (int c = 0; c < NCHUNK; ++c) {
    carry[(b * NCHUNK + c) * N + n] = P;
    P = fmaf(aS, P, f[c]);
  }
}

// ---------------- Kernel 3: y = (xs + dec*carry) @ C.T (+D*u if D!=0) ---------
__global__ __launch_bounds__(256) void y_gemm(const unsigned short* __restrict__ xsb,
                                              const float* __restrict__ carry,
                                              const float* __restrict__ dec,
                                              const float* __restrict__ Cm,
                                              const float* __restrict__ Dv,
                                              const float* __restrict__ u,
                                              float* __restrict__ y) {
  __shared__ __align__(16) char smem[33792];
  unsigned short (*Xs)[72] = reinterpret_cast<unsigned short (*)[72]>(smem);         // 9216 B
  unsigned short (*Cs)[72] = reinterpret_cast<unsigned short (*)[72]>(smem + 9216);  // 18432 B
  float (*T)[132] = reinterpret_cast<float (*)[132]>(smem);                          // 33792 B union
  __shared__ float ciS[64], Dsh[128];

  const int tid  = threadIdx.x;
  const int lane = tid & 63;
  const int wv   = tid >> 6;
  const int l15  = lane & 15;
  const int g    = lane >> 4;
  const int row0 = (blockIdx.x & 255) * 64;
  const int d0   = (blockIdx.x >> 8) * 128;

  if (tid < 64)  ciS[tid] = carry[row0 + tid];
  if (tid < 128) Dsh[tid] = Dv[d0 + tid];
  __syncthreads();

  // stage Xs with carry fixup: 512 ushort8 groups (2 per thread)
  #pragma unroll
  for (int i = 0; i < 2; ++i) {
    const int idx = tid + i * 256;
    const int r = idx >> 3, q = idx & 7;
    const uint4 xv = *reinterpret_cast<const uint4*>(&xsb[(long)(row0 + r) * N + q * 8]);
    const float4 dv0 = *reinterpret_cast<const float4*>(&dec[r * N + q * 8]);
    const float4 dv1 = *reinterpret_cast<const float4*>(&dec[r * N + q * 8 + 4]);
    float f[8];
    #pragma unroll
    for (int j = 0; j < 4; ++j) {
      const unsigned int wbits = (&xv.x)[j];
      f[2 * j]     = __uint_as_float(wbits << 16);
      f[2 * j + 1] = __uint_as_float(wbits & 0xFFFF0000u);
    }
    f[0] = fmaf(dv0.x, ciS[q * 8 + 0], f[0]);
    f[1] = fmaf(dv0.y, ciS[q * 8 + 1], f[1]);
    f[2] = fmaf(dv0.z, ciS[q * 8 + 2], f[2]);
    f[3] = fmaf(dv0.w, ciS[q * 8 + 3], f[3]);
    f[4] = fmaf(dv1.x, ciS[q * 8 + 4], f[4]);
    f[5] = fmaf(dv1.y, ciS[q * 8 + 5], f[5]);
    f[6] = fmaf(dv1.z, ciS[q * 8 + 6], f[6]);
    f[7] = fmaf(dv1.w, ciS[q * 8 + 7], f[7]);
    uint4 o = {pk2(f[0], f[1]), pk2(f[2], f[3]), pk2(f[4], f[5]), pk2(f[6], f[7])};
    *reinterpret_cast<uint4*>(&Xs[r][q * 8]) = o;
  }
  // stage Cs from f32 (L2-hot): 128 d x 64 n
  #pragma unroll
  for (int i = 0; i < 8; ++i) {
    const int idx = tid + i * 256;
    const int r = idx >> 4, q = idx & 15;
    const float4 v = *reinterpret_cast<const float4*>(&Cm[(long)(d0 + r) * N + q * 4]);
    uint2 o = {pk2(v.x, v.y), pk2(v.z, v.w)};
    *reinterpret_cast<uint2*>(&Cs[r][q * 4]) = o;
  }
  __syncthreads();

  bf16x8 af[2];
  #pragma unroll
  for (int ks = 0; ks < 2; ++ks)
    af[ks] = *reinterpret_cast<const bf16x8*>(&Xs[wv * 16 + l15][ks * 32 + g * 8]);

  f32x4 acc[8] = {};
  #pragma unroll
  for (int t = 0; t < 8; ++t) {
    #pragma unroll
    for (int ks = 0; ks < 2; ++ks) {
      const bf16x8 bfr = *reinterpret_cast<const bf16x8*>(
          &Cs[t * 16 + l15][ks * 32 + g * 8]);
      acc[t] = __builtin_amdgcn_mfma_f32_16x16x32_bf16(af[ks], bfr, acc[t], 0, 0, 0);
    }
  }

  // transpose via LDS -> coalesced float4 stores
  __syncthreads();
  #pragma unroll
  for (int t = 0; t < 8; ++t)
    #pragma unroll
    for (int r = 0; r < 4; ++r)
      T[wv * 16 + g * 4 + r][t * 16 + l15] = acc[t][r];
  __syncthreads();

  #pragma unroll
  for (int i = 0; i < 8; ++i) {
    const int id = tid + i * 256;
    const int r = id >> 5;
    const int q = id & 31;
    float4 v = *reinterpret_cast<const float4*>(&T[r][q * 4]);
    const float4 dd = *reinterpret_cast<const float4*>(&Dsh[q * 4]);
    if (dd.x != 0.0f || dd.y != 0.0f || dd.z != 0.0f || dd.w != 0.0f) {
      const float4 uu = *reinterpret_cast<const float4*>(
          &u[(long)(row0 + r) * DM + d0 + q * 4]);
      v.x = fmaf(dd.x, uu.x, v.x);
      v.y = fmaf(dd.y, uu.y, v.y);
      v.z = fmaf(dd.z, uu.z, v.z);
      v.w = fmaf(dd.w, uu.w, v.w);
    }
    *reinterpret_cast<float4*>(&y[(long)(row0 + r) * DM + d0 + q * 4]) = v;
  }
}

extern "C" void kernel_launch(void* const* d_in, const int* in_sizes, int n_in,
                              void* d_out, int out_size, void* d_ws, size_t ws_size,
                              hipStream_t stream) {
  const float* u      = (const float*)d_in[0];
  const float* Lambda = (const float*)d_in[1];
  const float* log_dt = (const float*)d_in[2];
  const float* Bm     = (const float*)d_in[3];
  const float* Cm     = (const float*)d_in[4];
  const float* Dv     = (const float*)d_in[5];
  float* y = (float*)d_out;

  const size_t planeB = (size_t)ROWS * N;              // 1M elems
  unsigned short* xsb = (unsigned short*)d_ws;         // 2 MB bf16
  float* F     = (float*)(xsb + planeB);               // 64 KB
  float* carry = F + (size_t)BATCH * NCHUNK * N;       // 64 KB
  float* dec   = carry + (size_t)BATCH * NCHUNK * N;   // 16 KB

  bu_scan<<<ROWS / 64, 256, 0, stream>>>(u, Bm, Lambda, log_dt, xsb, F);
  carry_scan<<<1, 256, 0, stream>>>(F, Lambda, log_dt, carry, dec);
  y_gemm<<<(ROWS / 64) * (DM / 128), 256, 0, stream>>>(xsb, carry, dec, Cm, Dv, u, y);
}